// Round 1
// baseline (240.449 us; speedup 1.0000x reference)
//
#include <hip/hip_runtime.h>

typedef __attribute__((ext_vector_type(8))) __bf16 bf16x8;
typedef __attribute__((ext_vector_type(4))) float f32x4;

#define LOG2E 1.4426950408889634f

// ---- workspace byte offsets ----
#define XT_OFF   0ul          // Xt  : bf16 [8][4096][256]  (x transposed, p-major)
#define TT_OFF   16777216ul   // Tt  : bf16 [8][2048][256]  (x_theta, n-major)
#define PT_OFF   25165824ul   // Pt  : bf16 [8][2048][256]  (x_phi, n-major)
#define G_OFF    33554432ul   // G   : bf16 [8][256][2048]  (x_g, c-major)
#define OT_OFF   41943040ul   // OT  : bf16 [8][4096][128]  (out_nl transposed, p-major)
#define W3_OFF   50331648ul   // W3  : bf16 [384][256] (theta/phi/g weights stacked)
#define WM_OFF   50528256ul   // Wm  : bf16 [256][128]
#define PART_OFF 50593792ul   // PART: f32  [8][32][2048] column-sum partials
#define L_OFF    52690944ul   // L   : f32  [8][2048] log2 of softmax denominators
#define WS_NEED  52756480ul

// ---------------- weights cast ----------------
__global__ __launch_bounds__(256) void k_weights(const float* wt, const float* wp,
                                                 const float* wg, const float* wm,
                                                 __bf16* W3, __bf16* Wm){
  int idx = blockIdx.x*256 + threadIdx.x;
  if (idx < 98304){
    float v = (idx < 32768) ? wt[idx] : (idx < 65536) ? wp[idx - 32768] : wg[idx - 65536];
    W3[idx] = (__bf16)v;
  } else if (idx < 131072){
    Wm[idx - 98304] = (__bf16)wm[idx - 98304];
  }
}

// ---------------- transpose+cast x: (b,256,4096) f32 -> Xt (b,4096,256) bf16 ----------------
__global__ __launch_bounds__(256) void k_xt(const float* x, __bf16* Xt){
  __shared__ float tile[64][65];
  int b = blockIdx.z, c0 = blockIdx.y*64, p0 = blockIdx.x*64;
  int t = threadIdx.x, col = t & 63, r0 = t >> 6;
  const float* xb = x + ((size_t)b*256 + c0)*4096 + p0;
  #pragma unroll
  for (int rr = 0; rr < 16; ++rr){
    int row = rr*4 + r0;
    tile[row][col] = xb[(size_t)row*4096 + col];
  }
  __syncthreads();
  __bf16* xo = Xt + ((size_t)b*4096 + p0)*256 + c0;
  #pragma unroll
  for (int rr = 0; rr < 16; ++rr){
    int prow = rr*4 + r0;
    xo[(size_t)prow*256 + col] = (__bf16)tile[col][prow];
  }
}

// ---------------- conv3: Xt(4096x256) * W3^T(384x256) -> theta/phi/g in attn layouts ----------------
__global__ __launch_bounds__(256) void k_conv3(const __bf16* Xt, const __bf16* W3,
                                               __bf16* Tt, __bf16* Pt, __bf16* G){
  __shared__ __bf16 As[128*72];
  __shared__ __bf16 Bs[64*72];
  int b = blockIdx.z, p0 = blockIdx.x*128, o0 = blockIdx.y*64;
  int tid = threadIdx.x, lane = tid & 63, wave = tid >> 6;
  int wm = wave >> 1, wn = wave & 1;
  f32x4 acc[4][2] = {};
  const __bf16* Ab = Xt + ((size_t)b*4096 + p0)*256;
  const __bf16* Bb = W3 + (size_t)o0*256;
  for (int kc = 0; kc < 4; ++kc){
    int k0 = kc*64;
    #pragma unroll
    for (int it = 0; it < 4; ++it){
      int s = tid + it*256, row = s >> 3, sk = s & 7;
      *(uint4*)&As[row*72 + sk*8] = *(const uint4*)(Ab + (size_t)row*256 + k0 + sk*8);
    }
    #pragma unroll
    for (int it = 0; it < 2; ++it){
      int s = tid + it*256, row = s >> 3, sk = s & 7;
      *(uint4*)&Bs[row*72 + sk*8] = *(const uint4*)(Bb + (size_t)row*256 + k0 + sk*8);
    }
    __syncthreads();
    #pragma unroll
    for (int ks = 0; ks < 2; ++ks){
      int koff = ks*32 + (lane>>4)*8;
      bf16x8 af[4], bfr[2];
      #pragma unroll
      for (int fm = 0; fm < 4; ++fm)
        af[fm] = *(const bf16x8*)&As[(wm*64 + fm*16 + (lane&15))*72 + koff];
      #pragma unroll
      for (int fn = 0; fn < 2; ++fn)
        bfr[fn] = *(const bf16x8*)&Bs[(wn*32 + fn*16 + (lane&15))*72 + koff];
      #pragma unroll
      for (int fm = 0; fm < 4; ++fm)
        #pragma unroll
        for (int fn = 0; fn < 2; ++fn)
          acc[fm][fn] = __builtin_amdgcn_mfma_f32_16x16x32_bf16(af[fm], bfr[fn], acc[fm][fn], 0, 0, 0);
    }
    __syncthreads();
  }
  // scatter per the reshape-view: flat = o*4096+p -> c = 2o+(p>>11), n = p&2047
  #pragma unroll
  for (int fm = 0; fm < 4; ++fm)
    #pragma unroll
    for (int fn = 0; fn < 2; ++fn)
      #pragma unroll
      for (int r = 0; r < 4; ++r){
        int p = p0 + wm*64 + fm*16 + (lane>>4)*4 + r;
        int o = o0 + wn*32 + fn*16 + (lane&15);
        __bf16 v = (__bf16)acc[fm][fn][r];
        int i = p & 2047, ph = p >> 11;
        if (o < 128)      Tt[((size_t)b*2048 + i)*256 + 2*o + ph] = v;
        else if (o < 256) Pt[((size_t)b*2048 + i)*256 + 2*(o-128) + ph] = v;
        else              G [((size_t)b*256 + 2*(o-256) + ph)*2048 + i] = v;
      }
}

// ---------------- pass A: column sums of exp(s) -> PART ----------------
__global__ __launch_bounds__(512) void k_colsum(const __bf16* Tt, const __bf16* Pt, float* PART){
  __shared__ __bf16 Ts[64*264];
  __shared__ __bf16 Ps[64*264];
  __shared__ float red[2][64];
  int b = blockIdx.y, it = blockIdx.x, i0 = it*64;
  int tid = threadIdx.x, lane = tid & 63, wave = tid >> 6;
  int wm = wave >> 2, wn = wave & 3;
  const __bf16* Tb = Tt + ((size_t)b*2048 + i0)*256;
  #pragma unroll
  for (int itc = 0; itc < 4; ++itc){
    int s = tid + itc*512, row = s >> 5, sk = s & 31;
    *(uint4*)&Ts[row*264 + sk*8] = *(const uint4*)(Tb + (size_t)row*256 + sk*8);
  }
  for (int ch = 0; ch < 32; ++ch){
    int j0 = ch*64;
    const __bf16* Pb = Pt + ((size_t)b*2048 + j0)*256;
    #pragma unroll
    for (int itc = 0; itc < 4; ++itc){
      int s = tid + itc*512, row = s >> 5, sk = s & 31;
      *(uint4*)&Ps[row*264 + sk*8] = *(const uint4*)(Pb + (size_t)row*256 + sk*8);
    }
    __syncthreads();
    f32x4 sa[2] = {};
    #pragma unroll
    for (int ks = 0; ks < 8; ++ks){
      int koff = ks*32 + (lane>>4)*8;
      bf16x8 bfr = *(const bf16x8*)&Ps[(wn*16 + (lane&15))*264 + koff];
      #pragma unroll
      for (int fm = 0; fm < 2; ++fm){
        bf16x8 af = *(const bf16x8*)&Ts[(wm*32 + fm*16 + (lane&15))*264 + koff];
        sa[fm] = __builtin_amdgcn_mfma_f32_16x16x32_bf16(af, bfr, sa[fm], 0, 0, 0);
      }
    }
    float v = 0.f;
    #pragma unroll
    for (int fm = 0; fm < 2; ++fm)
      #pragma unroll
      for (int r = 0; r < 4; ++r)
        v += exp2f(sa[fm][r] * LOG2E);
    v += __shfl_xor(v, 16);
    v += __shfl_xor(v, 32);
    if (lane < 16) red[wm][wn*16 + lane] = v;
    __syncthreads();
    if (tid < 64) PART[((size_t)b*32 + it)*2048 + j0 + tid] = red[0][tid] + red[1][tid];
    __syncthreads();
  }
}

// ---------------- reduce partials -> L = log2(D) ----------------
__global__ __launch_bounds__(256) void k_logd(const float* PART, float* L){
  int idx = blockIdx.x*256 + threadIdx.x;   // 16384
  int b = idx >> 11, j = idx & 2047;
  float s = 0.f;
  #pragma unroll
  for (int it = 0; it < 32; ++it) s += PART[((size_t)b*32 + it)*2048 + j];
  L[idx] = log2f(s);
}

// ---------------- pass B: recompute s, w=exp2(s*log2e - L), out = w @ g ----------------
__global__ __launch_bounds__(512) void k_attn(const __bf16* Tt, const __bf16* Pt,
                                              const __bf16* G, const float* L, __bf16* OT){
  __shared__ __bf16 Ts[64*264];
  __shared__ __bf16 Ps[64*264];
  __shared__ __bf16 Ss[64*72];
  int b = blockIdx.y, it = blockIdx.x, i0 = it*64;
  int tid = threadIdx.x, lane = tid & 63, wave = tid >> 6;
  int wm = wave >> 2, wn = wave & 3;
  const __bf16* Tb = Tt + ((size_t)b*2048 + i0)*256;
  #pragma unroll
  for (int itc = 0; itc < 4; ++itc){
    int s = tid + itc*512, row = s >> 5, sk = s & 31;
    *(uint4*)&Ts[row*264 + sk*8] = *(const uint4*)(Tb + (size_t)row*256 + sk*8);
  }
  f32x4 acc[2][4] = {};
  const __bf16* Gb = G + (size_t)b*256*2048;
  const float* Lb = L + (size_t)b*2048;
  for (int ch = 0; ch < 32; ++ch){
    int j0 = ch*64;
    const __bf16* Pb = Pt + ((size_t)b*2048 + j0)*256;
    #pragma unroll
    for (int itc = 0; itc < 4; ++itc){
      int s = tid + itc*512, row = s >> 5, sk = s & 31;
      *(uint4*)&Ps[row*264 + sk*8] = *(const uint4*)(Pb + (size_t)row*256 + sk*8);
    }
    __syncthreads();
    // QK for this j-chunk
    f32x4 sa[2] = {};
    #pragma unroll
    for (int ks = 0; ks < 8; ++ks){
      int koff = ks*32 + (lane>>4)*8;
      bf16x8 bfr = *(const bf16x8*)&Ps[(wn*16 + (lane&15))*264 + koff];
      #pragma unroll
      for (int fm = 0; fm < 2; ++fm){
        bf16x8 af = *(const bf16x8*)&Ts[(wm*32 + fm*16 + (lane&15))*264 + koff];
        sa[fm] = __builtin_amdgcn_mfma_f32_16x16x32_bf16(af, bfr, sa[fm], 0, 0, 0);
      }
    }
    // softmax weights -> Ss (bf16)
    {
      int jl = wn*16 + (lane&15);
      float Lv = Lb[j0 + jl];
      #pragma unroll
      for (int fm = 0; fm < 2; ++fm){
        int ib = wm*32 + fm*16 + (lane>>4)*4;
        #pragma unroll
        for (int r = 0; r < 4; ++r){
          float w = exp2f(sa[fm][r]*LOG2E - Lv);
          Ss[(ib + r)*72 + jl] = (__bf16)w;
        }
      }
    }
    __syncthreads();
    // PV: acc += Ss(64 x 64j) * G(64j x 256c'), B-frags straight from L2
    #pragma unroll
    for (int ks = 0; ks < 2; ++ks){
      int koff = ks*32 + (lane>>4)*8;
      bf16x8 af[2];
      #pragma unroll
      for (int fm = 0; fm < 2; ++fm)
        af[fm] = *(const bf16x8*)&Ss[(wm*32 + fm*16 + (lane&15))*72 + koff];
      #pragma unroll
      for (int fn = 0; fn < 4; ++fn){
        int cp = wn*64 + fn*16 + (lane&15);
        bf16x8 bfr = *(const bf16x8*)(Gb + (size_t)cp*2048 + j0 + koff);
        #pragma unroll
        for (int fm = 0; fm < 2; ++fm)
          acc[fm][fn] = __builtin_amdgcn_mfma_f32_16x16x32_bf16(af[fm], bfr, acc[fm][fn], 0, 0, 0);
      }
    }
    __syncthreads();
  }
  // epilogue: out[i][c'] -> OT[p][ic] with ic=c'>>1, p=(c'&1)*2048+i
  #pragma unroll
  for (int fm = 0; fm < 2; ++fm)
    #pragma unroll
    for (int fn = 0; fn < 4; ++fn)
      #pragma unroll
      for (int r = 0; r < 4; ++r){
        int i = i0 + wm*32 + fm*16 + (lane>>4)*4 + r;
        int cp = wn*64 + fn*16 + (lane&15);
        int p = ((cp & 1) << 11) + i;
        OT[((size_t)b*4096 + p)*128 + (cp >> 1)] = (__bf16)acc[fm][fn][r];
      }
}

// ---------------- mask conv + residual: OT(4096x128) * Wm^T(256x128) + x ----------------
__global__ __launch_bounds__(256) void k_mask(const __bf16* OT, const __bf16* Wm,
                                              const float* x, float* out){
  __shared__ __bf16 As[128*72];
  __shared__ __bf16 Bs[64*72];
  int b = blockIdx.z, p0 = blockIdx.x*128, o0 = blockIdx.y*64;
  int tid = threadIdx.x, lane = tid & 63, wave = tid >> 6;
  int wm = wave >> 1, wn = wave & 1;
  f32x4 acc[4][2] = {};
  const __bf16* Ab = OT + ((size_t)b*4096 + p0)*128;
  const __bf16* Bb = Wm + (size_t)o0*128;
  for (int kc = 0; kc < 2; ++kc){
    int k0 = kc*64;
    #pragma unroll
    for (int itc = 0; itc < 4; ++itc){
      int s = tid + itc*256, row = s >> 3, sk = s & 7;
      *(uint4*)&As[row*72 + sk*8] = *(const uint4*)(Ab + (size_t)row*128 + k0 + sk*8);
    }
    #pragma unroll
    for (int itc = 0; itc < 2; ++itc){
      int s = tid + itc*256, row = s >> 3, sk = s & 7;
      *(uint4*)&Bs[row*72 + sk*8] = *(const uint4*)(Bb + (size_t)row*128 + k0 + sk*8);
    }
    __syncthreads();
    #pragma unroll
    for (int ks = 0; ks < 2; ++ks){
      int koff = ks*32 + (lane>>4)*8;
      bf16x8 af[4], bfr[2];
      #pragma unroll
      for (int fm = 0; fm < 4; ++fm)
        af[fm] = *(const bf16x8*)&As[(wm*64 + fm*16 + (lane&15))*72 + koff];
      #pragma unroll
      for (int fn = 0; fn < 2; ++fn)
        bfr[fn] = *(const bf16x8*)&Bs[(wn*32 + fn*16 + (lane&15))*72 + koff];
      #pragma unroll
      for (int fm = 0; fm < 4; ++fm)
        #pragma unroll
        for (int fn = 0; fn < 2; ++fn)
          acc[fm][fn] = __builtin_amdgcn_mfma_f32_16x16x32_bf16(af[fm], bfr[fn], acc[fm][fn], 0, 0, 0);
    }
    __syncthreads();
  }
  #pragma unroll
  for (int fm = 0; fm < 4; ++fm)
    #pragma unroll
    for (int fn = 0; fn < 2; ++fn){
      int pb = p0 + wm*64 + fm*16 + (lane>>4)*4;
      int o = o0 + wn*32 + fn*16 + (lane&15);
      size_t idx = ((size_t)b*256 + o)*4096 + pb;
      f32x4 xv = *(const f32x4*)(x + idx);
      f32x4 ov = acc[fm][fn] + xv;
      *(f32x4*)(out + idx) = ov;
    }
}

extern "C" void kernel_launch(void* const* d_in, const int* in_sizes, int n_in,
                              void* d_out, int out_size, void* d_ws, size_t ws_size,
                              hipStream_t stream){
  if (ws_size < WS_NEED) return;  // workspace too small; fail visibly
  const float* x  = (const float*)d_in[0];
  const float* wt = (const float*)d_in[1];
  const float* wp = (const float*)d_in[2];
  const float* wg = (const float*)d_in[3];
  const float* wm = (const float*)d_in[4];
  char* ws = (char*)d_ws;
  __bf16* Xt  = (__bf16*)(ws + XT_OFF);
  __bf16* Tt  = (__bf16*)(ws + TT_OFF);
  __bf16* Pt  = (__bf16*)(ws + PT_OFF);
  __bf16* G   = (__bf16*)(ws + G_OFF);
  __bf16* OT  = (__bf16*)(ws + OT_OFF);
  __bf16* W3  = (__bf16*)(ws + W3_OFF);
  __bf16* Wm  = (__bf16*)(ws + WM_OFF);
  float* PART = (float*)(ws + PART_OFF);
  float* L    = (float*)(ws + L_OFF);
  float* out  = (float*)d_out;

  k_weights<<<512, 256, 0, stream>>>(wt, wp, wg, wm, W3, Wm);
  k_xt<<<dim3(64, 4, 8), 256, 0, stream>>>(x, Xt);
  k_conv3<<<dim3(32, 6, 8), 256, 0, stream>>>(Xt, W3, Tt, Pt, G);
  k_colsum<<<dim3(32, 8), 512, 0, stream>>>(Tt, Pt, PART);
  k_logd<<<64, 256, 0, stream>>>(PART, L);
  k_attn<<<dim3(32, 8), 512, 0, stream>>>(Tt, Pt, G, L, OT);
  k_mask<<<dim3(32, 4, 8), 256, 0, stream>>>(OT, Wm, x, out);
}